// Round 3
// baseline (344.799 us; speedup 1.0000x reference)
//
#include <hip/hip_runtime.h>

#define D   640
#define NB  2048
#define LQ  32

// ---------------------------------------------------------------------------
// Kernel A: t[b,:] = (sum_d v[b,d]) * v[b,:] + k[b,:]
// One block per batch b. 160 float4 per row; threads 0..159 each own one f4.
// ---------------------------------------------------------------------------
__global__ __launch_bounds__(256) void compute_t_kernel(
    const float* __restrict__ v, const float* __restrict__ kin,
    float* __restrict__ T) {
  const int b   = blockIdx.x;
  const int tid = threadIdx.x;
  const float4* v4 = (const float4*)(v + b * D);
  const float4* k4 = (const float4*)(kin + b * D);

  float4 vv = make_float4(0.f, 0.f, 0.f, 0.f);
  if (tid < 160) vv = v4[tid];
  float s = vv.x + vv.y + vv.z + vv.w;

  // wave reduce (64 lanes)
  #pragma unroll
  for (int off = 32; off; off >>= 1) s += __shfl_xor(s, off);

  __shared__ float red[4];
  if ((tid & 63) == 0) red[tid >> 6] = s;
  __syncthreads();
  const float tot = red[0] + red[1] + red[2] + red[3];

  if (tid < 160) {
    float4 kv = k4[tid];
    float4 t;
    t.x = tot * vv.x + kv.x;
    t.y = tot * vv.y + kv.y;
    t.z = tot * vv.z + kv.z;
    t.w = tot * vv.w + kv.w;
    ((float4*)(T + b * D))[tid] = t;
  }
}

// ---------------------------------------------------------------------------
// Kernel B: G[m,n] = (sum_k T[m,k] * W[n,k] + b_fc[n]) * gamma1[n]
// fp32 tiled GEMM (no fp32 MFMA on CDNA4). 64x64 tile, BK=16, 256 threads,
// 4x4 micro-tile per thread. Both A and B are K-contiguous (TN layout).
// ---------------------------------------------------------------------------
#define BM 64
#define BN 64
#define BK 16

__global__ __launch_bounds__(256) void gemm_tn_kernel(
    const float* __restrict__ T, const float* __restrict__ W,
    const float* __restrict__ bfc, const float* __restrict__ g1,
    float* __restrict__ G) {
  // +4 pad: row stride 68 floats = 272B (16B-multiple, keeps float4 reads
  // aligned and staggers banks). __align__(16) guarantees the b128 path.
  __shared__ __align__(16) float As[BK][BM + 4];
  __shared__ __align__(16) float Bs[BK][BN + 4];

  const int tid = threadIdx.x;
  const int bm  = blockIdx.x * BM;
  const int bn  = blockIdx.y * BN;

  const int lr = tid >> 2;          // 0..63 : tile row being loaded
  const int lc = (tid & 3) << 2;    // 0,4,8,12 : k-offset of the float4

  const int tm = (tid & 15) << 2;   // m within tile for compute
  const int tn = (tid >> 4) << 2;   // n within tile for compute

  const float* Arow = T + (bm + lr) * D;
  const float* Brow = W + (bn + lr) * D;

  float acc[4][4] = {};

  for (int k0 = 0; k0 < D; k0 += BK) {
    float4 a = *(const float4*)(Arow + k0 + lc);
    float4 b = *(const float4*)(Brow + k0 + lc);
    __syncthreads();   // protect previous iteration's LDS reads
    As[lc + 0][lr] = a.x; As[lc + 1][lr] = a.y;
    As[lc + 2][lr] = a.z; As[lc + 3][lr] = a.w;
    Bs[lc + 0][lr] = b.x; Bs[lc + 1][lr] = b.y;
    Bs[lc + 2][lr] = b.z; Bs[lc + 3][lr] = b.w;
    __syncthreads();

    #pragma unroll
    for (int kk = 0; kk < BK; ++kk) {
      float4 av = *(const float4*)&As[kk][tm];
      float4 bv = *(const float4*)&Bs[kk][tn];
      acc[0][0] += av.x * bv.x; acc[0][1] += av.x * bv.y;
      acc[0][2] += av.x * bv.z; acc[0][3] += av.x * bv.w;
      acc[1][0] += av.y * bv.x; acc[1][1] += av.y * bv.y;
      acc[1][2] += av.y * bv.z; acc[1][3] += av.y * bv.w;
      acc[2][0] += av.z * bv.x; acc[2][1] += av.z * bv.y;
      acc[2][2] += av.z * bv.z; acc[2][3] += av.z * bv.w;
      acc[3][0] += av.w * bv.x; acc[3][1] += av.w * bv.y;
      acc[3][2] += av.w * bv.z; acc[3][3] += av.w * bv.w;
    }
  }

  // epilogue: add bias, scale by gamma1, store
  const int n = bn + tn;
  const float4 bf = *(const float4*)(bfc + n);
  const float4 gg = *(const float4*)(g1 + n);
  #pragma unroll
  for (int i = 0; i < 4; ++i) {
    const int m = bm + tm + i;
    float4 r;
    r.x = (acc[i][0] + bf.x) * gg.x;
    r.y = (acc[i][1] + bf.y) * gg.y;
    r.z = (acc[i][2] + bf.z) * gg.z;
    r.w = (acc[i][3] + bf.w) * gg.w;
    *(float4*)(G + m * D + n) = r;
  }
}

// ---------------------------------------------------------------------------
// Kernel C: out[r,:] = LayerNorm(q[r,:] + G[r>>5,:])   (row length 640)
// One wave per row; 160 float4 per row -> lane owns f4 {lane, lane+64,
// lane+128(if lane<32)}. Wave shfl reduction for mean/var.
// ---------------------------------------------------------------------------
__global__ __launch_bounds__(256) void ln_fused_kernel(
    const float* __restrict__ q, const float* __restrict__ G,
    const float* __restrict__ lw, const float* __restrict__ lb,
    float* __restrict__ out) {
  const int lane = threadIdx.x & 63;
  const int wv   = threadIdx.x >> 6;
  const int r    = blockIdx.x * 4 + wv;       // row 0..65535
  const int b    = r >> 5;                    // batch

  const float4* q4 = (const float4*)(q + r * D);
  const float4* g4 = (const float4*)(G + b * D);

  const int nchunk = (lane < 32) ? 3 : 2;
  float4 z[3];
  float s = 0.f, ss = 0.f;

  #pragma unroll
  for (int i = 0; i < 3; ++i) {
    if (i < nchunk) {
      const int idx = lane + 64 * i;
      float4 a = q4[idx];
      float4 g = g4[idx];
      z[i].x = a.x + g.x; z[i].y = a.y + g.y;
      z[i].z = a.z + g.z; z[i].w = a.w + g.w;
      s  += z[i].x + z[i].y + z[i].z + z[i].w;
      ss += z[i].x * z[i].x + z[i].y * z[i].y
          + z[i].z * z[i].z + z[i].w * z[i].w;
    }
  }

  #pragma unroll
  for (int off = 32; off; off >>= 1) {
    s  += __shfl_xor(s, off);
    ss += __shfl_xor(ss, off);
  }

  const float inv_n = 1.0f / (float)D;
  const float mean  = s * inv_n;
  const float var   = ss * inv_n - mean * mean;
  const float rs    = rsqrtf(var + 1e-5f);

  float4* o4 = (float4*)(out + r * D);
  const float4* w4 = (const float4*)lw;
  const float4* b4 = (const float4*)lb;

  #pragma unroll
  for (int i = 0; i < 3; ++i) {
    if (i < nchunk) {
      const int idx = lane + 64 * i;
      float4 w = w4[idx];
      float4 bb = b4[idx];
      float4 o;
      o.x = (z[i].x - mean) * rs * w.x + bb.x;
      o.y = (z[i].y - mean) * rs * w.y + bb.y;
      o.z = (z[i].z - mean) * rs * w.z + bb.z;
      o.w = (z[i].w - mean) * rs * w.w + bb.w;
      o4[idx] = o;
    }
  }
}

// ---------------------------------------------------------------------------
extern "C" void kernel_launch(void* const* d_in, const int* in_sizes, int n_in,
                              void* d_out, int out_size, void* d_ws, size_t ws_size,
                              hipStream_t stream) {
  const float* q    = (const float*)d_in[0];
  const float* k    = (const float*)d_in[1];
  const float* v    = (const float*)d_in[2];
  const float* w_fc = (const float*)d_in[3];
  const float* b_fc = (const float*)d_in[4];
  const float* g1   = (const float*)d_in[5];
  const float* lw   = (const float*)d_in[6];
  const float* lb   = (const float*)d_in[7];
  float* out = (float*)d_out;

  float* T = (float*)d_ws;            // 2048*640 floats = 5.24 MB
  float* G = T + NB * D;              // 2048*640 floats = 5.24 MB

  compute_t_kernel<<<NB, 256, 0, stream>>>(v, k, T);

  dim3 g2(NB / BM, D / BN);           // 32 x 10
  gemm_tn_kernel<<<g2, 256, 0, stream>>>(T, w_fc, b_fc, g1, G);

  const int rows = NB * LQ;           // 65536
  ln_fused_kernel<<<rows / 4, 256, 0, stream>>>(q, G, lw, lb, out);
}